// Round 2
// baseline (252.570 us; speedup 1.0000x reference)
//
#include <hip/hip_runtime.h>

#define GRID_RES 128
#define N_RAYS 65536
#define N_STEPS 128
#define STEP_SIZE 0.001f
#define SEG 8
#define STEPS_PER (N_STEPS / SEG)   // 16

__device__ __forceinline__ float sigmoidf_fast(float x) {
    return 1.0f / (1.0f + __expf(-x));
}

__global__ __launch_bounds__(256, 8) void vr_kernel(
    const float* __restrict__ data,
    const float* __restrict__ origins,
    const float* __restrict__ dirs,
    const float* __restrict__ viewdirs,
    float* __restrict__ out)
{
    int gid = blockIdx.x * blockDim.x + threadIdx.x;
    int ray = gid >> 3;        // 8 lanes per ray
    int seg = gid & 7;
    if (ray >= N_RAYS) return;

    float ox = origins[3*ray+0], oy = origins[3*ray+1], oz = origins[3*ray+2];
    float dx = dirs[3*ray+0],    dy = dirs[3*ray+1],    dz = dirs[3*ray+2];
    float vx = viewdirs[3*ray+0], vy = viewdirs[3*ray+1], vz = viewdirs[3*ray+2];

    // normalize dirs: match numpy rounding (no fma contraction, sqrt+divide)
    {
        float s = __fadd_rn(__fadd_rn(__fmul_rn(dx,dx), __fmul_rn(dy,dy)), __fmul_rn(dz,dz));
        float n = sqrtf(s);
        dx = __fdiv_rn(dx, n); dy = __fdiv_rn(dy, n); dz = __fdiv_rn(dz, n);
    }
    {
        float s = __fadd_rn(__fadd_rn(__fmul_rn(vx,vx), __fmul_rn(vy,vy)), __fmul_rn(vz,vz));
        float n = sqrtf(s);
        vx = __fdiv_rn(vx, n); vy = __fdiv_rn(vy, n); vz = __fdiv_rn(vz, n);
    }

    float invx = __fdiv_rn(1.0f, __fadd_rn(dx, 1e-9f));
    float invy = __fdiv_rn(1.0f, __fadd_rn(dy, 1e-9f));
    float invz = __fdiv_rn(1.0f, __fadd_rn(dz, 1e-9f));

    // dda_unit
    float t1x = __fmul_rn(-ox, invx), t1y = __fmul_rn(-oy, invy), t1z = __fmul_rn(-oz, invz);
    float t2x = __fadd_rn(t1x, invx), t2y = __fadd_rn(t1y, invy), t2z = __fadd_rn(t1z, invz);
    float tmin = fmaxf(fmaxf(fminf(t1x,t2x), fminf(t1y,t2y)), fminf(t1z,t2z));
    tmin = fmaxf(tmin, 0.0f);
    float tmax = fminf(fminf(fmaxf(t1x,t2x), fmaxf(t1y,t2y)), fmaxf(t1z,t2z));
    tmax = fminf(tmax, 1e9f);
    float dt = __fmul_rn(fmaxf(__fsub_rn(tmax, tmin), 0.0f), (1.0f/(float)N_STEPS)); // /128 exact
    float delta_t = __fadd_rn(dt, STEP_SIZE);

    // SH basis
    const float sh0 = 0.28209479177387814f;
    float sh1 = -0.4886025119029199f * vy;
    float sh2 =  0.4886025119029199f * vz;
    float sh3 = -0.4886025119029199f * vx;
    float sh4 =  1.0925484305920792f * vx * vy;
    float sh5 = -1.0925484305920792f * vy * vz;
    float sh6 =  0.31539156525252005f * (2.0f*vz*vz - vx*vx - vy*vy);
    float sh7 = -1.0925484305920792f * vx * vz;
    float sh8 =  0.5462742152960396f * (vx*vx - vy*vy);

    float light = 1.0f;                // local (within-segment) transmittance chain
    float o_r = 0.0f, o_g = 0.0f, o_b = 0.0f;

    int i0 = seg * STEPS_PER;

    #pragma unroll 4
    for (int k = 0; k < STEPS_PER; ++k) {
        int i = i0 + k;
        // t = tmin + (i+0.5)*dt — identical arithmetic to the monolithic version
        float t = __fadd_rn(tmin, __fmul_rn((float)i + 0.5f, dt));
        float px = __fadd_rn(ox, __fmul_rn(t, dx));
        float py = __fadd_rn(oy, __fmul_rn(t, dy));
        float pz = __fadd_rn(oz, __fmul_rn(t, dz));
        int ix = (int)(px * (float)GRID_RES);
        int iy = (int)(py * (float)GRID_RES);
        int iz = (int)(pz * (float)GRID_RES);
        ix = min(max(ix, 0), GRID_RES-1);
        iy = min(max(iy, 0), GRID_RES-1);
        iz = min(max(iz, 0), GRID_RES-1);

        unsigned lin = (unsigned)(((ix << 7) | iy) << 7 | iz);
        const float4* vp = (const float4*)(data + 28u * lin);
        float4 c0 = vp[0];
        float4 c1 = vp[1];
        float4 c2 = vp[2];
        float4 c3 = vp[3];
        float4 c4 = vp[4];
        float4 c5 = vp[5];
        float4 c6 = vp[6];

        float sigma = fmaxf(c6.w, 0.0f);
        float att = __expf(-delta_t * sigma);
        float w = light * (1.0f - att);

        float r = sh0*c0.x + sh1*c0.y + sh2*c0.z + sh3*c0.w
                + sh4*c1.x + sh5*c1.y + sh6*c1.z + sh7*c1.w + sh8*c2.x;
        float g = sh0*c2.y + sh1*c2.z + sh2*c2.w + sh3*c3.x
                + sh4*c3.y + sh5*c3.z + sh6*c3.w + sh7*c4.x + sh8*c4.y;
        float b = sh0*c4.z + sh1*c4.w + sh2*c5.x + sh3*c5.y
                + sh4*c5.z + sh5*c5.w + sh6*c6.x + sh7*c6.y + sh8*c6.z;

        o_r = fmaf(w, sigmoidf_fast(r), o_r);
        o_g = fmaf(w, sigmoidf_fast(g), o_g);
        o_b = fmaf(w, sigmoidf_fast(b), o_b);
        light *= att;
    }

    // ---- cross-lane composition over the 8 segments of this ray ----
    // Inclusive prefix product of segment transmittances (width-8 groups).
    float incl = light;
    {
        float u;
        u = __shfl_up(incl, 1, 8); if ((gid & 7) >= 1) incl *= u;
        u = __shfl_up(incl, 2, 8); if ((gid & 7) >= 2) incl *= u;
        u = __shfl_up(incl, 4, 8); if ((gid & 7) >= 4) incl *= u;
    }
    // Exclusive prefix: shift right by one within the group, lane0 = 1.
    float prefix = __shfl_up(incl, 1, 8);
    if ((gid & 7) == 0) prefix = 1.0f;

    float cr = prefix * o_r;
    float cg = prefix * o_g;
    float cb = prefix * o_b;
    // Sum contributions across the 8 lanes.
    cr += __shfl_xor(cr, 1, 8); cg += __shfl_xor(cg, 1, 8); cb += __shfl_xor(cb, 1, 8);
    cr += __shfl_xor(cr, 2, 8); cg += __shfl_xor(cg, 2, 8); cb += __shfl_xor(cb, 2, 8);
    cr += __shfl_xor(cr, 4, 8); cg += __shfl_xor(cg, 4, 8); cb += __shfl_xor(cb, 4, 8);
    // Total transmittance = inclusive prefix at lane 7.
    float total_light = __shfl(incl, 7, 8);

    if ((gid & 7) == 0) {
        out[3*ray+0] = cr + total_light;   // BG = 1.0
        out[3*ray+1] = cg + total_light;
        out[3*ray+2] = cb + total_light;
    }
}

extern "C" void kernel_launch(void* const* d_in, const int* in_sizes, int n_in,
                              void* d_out, int out_size, void* d_ws, size_t ws_size,
                              hipStream_t stream) {
    const float* data     = (const float*)d_in[0];
    const float* origins  = (const float*)d_in[1];
    const float* dirs     = (const float*)d_in[2];
    const float* viewdirs = (const float*)d_in[3];
    float* out = (float*)d_out;

    dim3 block(256);
    dim3 grid((N_RAYS * SEG) / 256);
    vr_kernel<<<grid, block, 0, stream>>>(data, origins, dirs, viewdirs, out);
}

// Round 3
// 166.846 us; speedup vs baseline: 1.5138x; 1.5138x over previous
//
#include <hip/hip_runtime.h>

#define GRID_RES 128
#define N_RAYS 65536
#define N_STEPS 128
#define STEP_SIZE 0.001f
#define SEG 2
#define STEPS_PER (N_STEPS / SEG)   // 64

__device__ __forceinline__ float sigmoidf_fast(float x) {
    return 1.0f / (1.0f + __expf(-x));
}

__global__ __launch_bounds__(256) void vr_kernel(
    const float* __restrict__ data,
    const float* __restrict__ origins,
    const float* __restrict__ dirs,
    const float* __restrict__ viewdirs,
    float* __restrict__ out)
{
    int gid = blockIdx.x * blockDim.x + threadIdx.x;
    int ray = gid >> 1;        // 2 lanes per ray
    int seg = gid & 1;

    float ox = origins[3*ray+0], oy = origins[3*ray+1], oz = origins[3*ray+2];
    float dx = dirs[3*ray+0],    dy = dirs[3*ray+1],    dz = dirs[3*ray+2];
    float vx = viewdirs[3*ray+0], vy = viewdirs[3*ray+1], vz = viewdirs[3*ray+2];

    // normalize dirs: match numpy rounding (no fma contraction, sqrt+divide)
    {
        float s = __fadd_rn(__fadd_rn(__fmul_rn(dx,dx), __fmul_rn(dy,dy)), __fmul_rn(dz,dz));
        float n = sqrtf(s);
        dx = __fdiv_rn(dx, n); dy = __fdiv_rn(dy, n); dz = __fdiv_rn(dz, n);
    }
    {
        float s = __fadd_rn(__fadd_rn(__fmul_rn(vx,vx), __fmul_rn(vy,vy)), __fmul_rn(vz,vz));
        float n = sqrtf(s);
        vx = __fdiv_rn(vx, n); vy = __fdiv_rn(vy, n); vz = __fdiv_rn(vz, n);
    }

    float invx = __fdiv_rn(1.0f, __fadd_rn(dx, 1e-9f));
    float invy = __fdiv_rn(1.0f, __fadd_rn(dy, 1e-9f));
    float invz = __fdiv_rn(1.0f, __fadd_rn(dz, 1e-9f));

    // dda_unit
    float t1x = __fmul_rn(-ox, invx), t1y = __fmul_rn(-oy, invy), t1z = __fmul_rn(-oz, invz);
    float t2x = __fadd_rn(t1x, invx), t2y = __fadd_rn(t1y, invy), t2z = __fadd_rn(t1z, invz);
    float tmin = fmaxf(fmaxf(fminf(t1x,t2x), fminf(t1y,t2y)), fminf(t1z,t2z));
    tmin = fmaxf(tmin, 0.0f);
    float tmax = fminf(fminf(fmaxf(t1x,t2x), fmaxf(t1y,t2y)), fmaxf(t1z,t2z));
    tmax = fminf(tmax, 1e9f);
    float dt = __fmul_rn(fmaxf(__fsub_rn(tmax, tmin), 0.0f), (1.0f/(float)N_STEPS)); // /128 exact
    float delta_t = __fadd_rn(dt, STEP_SIZE);

    // SH basis
    const float sh0 = 0.28209479177387814f;
    float sh1 = -0.4886025119029199f * vy;
    float sh2 =  0.4886025119029199f * vz;
    float sh3 = -0.4886025119029199f * vx;
    float sh4 =  1.0925484305920792f * vx * vy;
    float sh5 = -1.0925484305920792f * vy * vz;
    float sh6 =  0.31539156525252005f * (2.0f*vz*vz - vx*vx - vy*vy);
    float sh7 = -1.0925484305920792f * vx * vz;
    float sh8 =  0.5462742152960396f * (vx*vx - vy*vy);

    float light = 1.0f;
    float o_r = 0.0f, o_g = 0.0f, o_b = 0.0f;

    const int i0 = seg * STEPS_PER;

    // voxel record address for absolute step i (bit-identical arithmetic to R1)
    auto addr = [&](int i) -> const float4* {
        float t = __fadd_rn(tmin, __fmul_rn((float)i + 0.5f, dt));
        float px = __fadd_rn(ox, __fmul_rn(t, dx));
        float py = __fadd_rn(oy, __fmul_rn(t, dy));
        float pz = __fadd_rn(oz, __fmul_rn(t, dz));
        int ix = (int)(px * (float)GRID_RES);
        int iy = (int)(py * (float)GRID_RES);
        int iz = (int)(pz * (float)GRID_RES);
        ix = min(max(ix, 0), GRID_RES-1);
        iy = min(max(iy, 0), GRID_RES-1);
        iz = min(max(iz, 0), GRID_RES-1);
        unsigned lin = (unsigned)(((ix << 7) | iy) << 7 | iz);
        return (const float4*)(data + 28u * lin);
    };

    // ---- software pipeline, depth 2: prefetch step k+1 while shading step k ----
    const float4* vp = addr(i0);
    float4 c0 = vp[0], c1 = vp[1], c2 = vp[2], c3 = vp[3], c4 = vp[4], c5 = vp[5], c6 = vp[6];

    for (int k = 0; k < STEPS_PER; ++k) {
        // prefetch next step (k==STEPS_PER-1 prefetches a clamped/valid record; harmless)
        const float4* np = addr(i0 + k + 1);
        float4 n0 = np[0], n1 = np[1], n2 = np[2], n3 = np[3], n4 = np[4], n5 = np[5], n6 = np[6];

        float sigma = fmaxf(c6.w, 0.0f);
        float att = __expf(-delta_t * sigma);
        float w = light * (1.0f - att);

        float r = sh0*c0.x + sh1*c0.y + sh2*c0.z + sh3*c0.w
                + sh4*c1.x + sh5*c1.y + sh6*c1.z + sh7*c1.w + sh8*c2.x;
        float g = sh0*c2.y + sh1*c2.z + sh2*c2.w + sh3*c3.x
                + sh4*c3.y + sh5*c3.z + sh6*c3.w + sh7*c4.x + sh8*c4.y;
        float b = sh0*c4.z + sh1*c4.w + sh2*c5.x + sh3*c5.y
                + sh4*c5.z + sh5*c5.w + sh6*c6.x + sh7*c6.y + sh8*c6.z;

        o_r = fmaf(w, sigmoidf_fast(r), o_r);
        o_g = fmaf(w, sigmoidf_fast(g), o_g);
        o_b = fmaf(w, sigmoidf_fast(b), o_b);
        light *= att;

        c0 = n0; c1 = n1; c2 = n2; c3 = n3; c4 = n4; c5 = n5; c6 = n6;
    }

    // ---- compose the 2 segments of this ray across the lane pair ----
    float otherLight = __shfl_xor(light, 1, 2);          // partner segment's transmittance
    float prefix = (seg == 0) ? 1.0f : otherLight;       // transmittance before my segment
    float total_light = light * otherLight;              // identical on both lanes

    float cr = prefix * o_r;
    float cg = prefix * o_g;
    float cb = prefix * o_b;
    cr += __shfl_xor(cr, 1, 2);
    cg += __shfl_xor(cg, 1, 2);
    cb += __shfl_xor(cb, 1, 2);

    if (seg == 0) {
        out[3*ray+0] = cr + total_light;   // BG = 1.0
        out[3*ray+1] = cg + total_light;
        out[3*ray+2] = cb + total_light;
    }
}

extern "C" void kernel_launch(void* const* d_in, const int* in_sizes, int n_in,
                              void* d_out, int out_size, void* d_ws, size_t ws_size,
                              hipStream_t stream) {
    const float* data     = (const float*)d_in[0];
    const float* origins  = (const float*)d_in[1];
    const float* dirs     = (const float*)d_in[2];
    const float* viewdirs = (const float*)d_in[3];
    float* out = (float*)d_out;

    dim3 block(256);
    dim3 grid((N_RAYS * SEG) / 256);
    vr_kernel<<<grid, block, 0, stream>>>(data, origins, dirs, viewdirs, out);
}

// Round 4
// 138.075 us; speedup vs baseline: 1.8292x; 1.2084x over previous
//
#include <hip/hip_runtime.h>

#define GRID_RES 128
#define N_RAYS 65536
#define N_STEPS 128
#define STEP_SIZE 0.001f

__device__ __forceinline__ float sigmoidf_fast(float x) {
    return 1.0f / (1.0f + __expf(-x));
}

// DPP quad_perm helpers (VALU cross-lane within each aligned group of 4 lanes)
__device__ __forceinline__ float quad_dpp_xor1(float x) {
    return __int_as_float(__builtin_amdgcn_update_dpp(0, __float_as_int(x), 0xB1, 0xF, 0xF, true)); // [1,0,3,2]
}
__device__ __forceinline__ float quad_dpp_xor2(float x) {
    return __int_as_float(__builtin_amdgcn_update_dpp(0, __float_as_int(x), 0x4E, 0xF, 0xF, true)); // [2,3,0,1]
}
__device__ __forceinline__ float quad_bcast3(float x) {
    return __int_as_float(__builtin_amdgcn_update_dpp(0, __float_as_int(x), 0xFF, 0xF, 0xF, true)); // [3,3,3,3]
}
__device__ __forceinline__ float quad_sum(float x) {
    x += quad_dpp_xor1(x);
    x += quad_dpp_xor2(x);
    return x;
}

__global__ __launch_bounds__(256) void vr_kernel(
    const float* __restrict__ data,
    const float* __restrict__ origins,
    const float* __restrict__ dirs,
    const float* __restrict__ viewdirs,
    float* __restrict__ out)
{
    int gid = blockIdx.x * blockDim.x + threadIdx.x;
    int ray = gid >> 2;        // 4 cooperative lanes per ray
    int l   = gid & 3;

    float ox = origins[3*ray+0], oy = origins[3*ray+1], oz = origins[3*ray+2];
    float dx = dirs[3*ray+0],    dy = dirs[3*ray+1],    dz = dirs[3*ray+2];
    float vx = viewdirs[3*ray+0], vy = viewdirs[3*ray+1], vz = viewdirs[3*ray+2];

    // normalize (numpy rounding: no fma contraction, sqrt+divide) — identical on all 4 lanes
    {
        float s = __fadd_rn(__fadd_rn(__fmul_rn(dx,dx), __fmul_rn(dy,dy)), __fmul_rn(dz,dz));
        float n = sqrtf(s);
        dx = __fdiv_rn(dx, n); dy = __fdiv_rn(dy, n); dz = __fdiv_rn(dz, n);
    }
    {
        float s = __fadd_rn(__fadd_rn(__fmul_rn(vx,vx), __fmul_rn(vy,vy)), __fmul_rn(vz,vz));
        float n = sqrtf(s);
        vx = __fdiv_rn(vx, n); vy = __fdiv_rn(vy, n); vz = __fdiv_rn(vz, n);
    }

    float invx = __fdiv_rn(1.0f, __fadd_rn(dx, 1e-9f));
    float invy = __fdiv_rn(1.0f, __fadd_rn(dy, 1e-9f));
    float invz = __fdiv_rn(1.0f, __fadd_rn(dz, 1e-9f));

    float t1x = __fmul_rn(-ox, invx), t1y = __fmul_rn(-oy, invy), t1z = __fmul_rn(-oz, invz);
    float t2x = __fadd_rn(t1x, invx), t2y = __fadd_rn(t1y, invy), t2z = __fadd_rn(t1z, invz);
    float tmin = fmaxf(fmaxf(fminf(t1x,t2x), fminf(t1y,t2y)), fminf(t1z,t2z));
    tmin = fmaxf(tmin, 0.0f);
    float tmax = fminf(fminf(fmaxf(t1x,t2x), fmaxf(t1y,t2y)), fmaxf(t1z,t2z));
    tmax = fminf(tmax, 1e9f);
    float dt = __fmul_rn(fmaxf(__fsub_rn(tmax, tmin), 0.0f), (1.0f/(float)N_STEPS));
    float delta_t = __fadd_rn(dt, STEP_SIZE);

    // SH basis
    const float sh0 = 0.28209479177387814f;
    float sh1 = -0.4886025119029199f * vy;
    float sh2 =  0.4886025119029199f * vz;
    float sh3 = -0.4886025119029199f * vx;
    float sh4 =  1.0925484305920792f * vx * vy;
    float sh5 = -1.0925484305920792f * vy * vz;
    float sh6 =  0.31539156525252005f * (2.0f*vz*vz - vx*vx - vy*vy);
    float sh7 = -1.0925484305920792f * vx * vz;
    float sh8 =  0.5462742152960396f * (vx*vx - vy*vy);

    // Per-lane channel-routed weights for components c = 8l..8l+7.
    // comp c: channel c/9 (r,g,b), basis c%9, sigma at c==27 (handled separately).
    float wr[8], wg[8], wb[8];
    #pragma unroll
    for (int m = 0; m < 8; ++m) {
        int c  = 8*l + m;
        int cb = c % 9;
        float s = sh0;
        s = (cb==1) ? sh1 : s;
        s = (cb==2) ? sh2 : s;
        s = (cb==3) ? sh3 : s;
        s = (cb==4) ? sh4 : s;
        s = (cb==5) ? sh5 : s;
        s = (cb==6) ? sh6 : s;
        s = (cb==7) ? sh7 : s;
        s = (cb==8) ? sh8 : s;
        wr[m] = (c < 9)            ? s : 0.0f;
        wg[m] = (c >= 9 && c < 18) ? s : 0.0f;
        wb[m] = (c >= 18 && c < 27)? s : 0.0f;
    }

    // Per-lane float offsets within a record: A = comps 8l.., B = comps 8l+4..
    // lane3's B clamped to offset 24 (in-bounds; its weights are all zero).
    unsigned offA = 8u * (unsigned)l;
    unsigned offB = (l < 3) ? (8u * (unsigned)l + 4u) : 24u;

    float light = 1.0f;
    float o_r = 0.0f, o_g = 0.0f, o_b = 0.0f;

    #pragma unroll 2
    for (int i = 0; i < N_STEPS; ++i) {
        // voxel index: bit-identical chain to the validated monolithic kernel
        float t = __fadd_rn(tmin, __fmul_rn((float)i + 0.5f, dt));
        float px = __fadd_rn(ox, __fmul_rn(t, dx));
        float py = __fadd_rn(oy, __fmul_rn(t, dy));
        float pz = __fadd_rn(oz, __fmul_rn(t, dz));
        int ix = (int)(px * (float)GRID_RES);
        int iy = (int)(py * (float)GRID_RES);
        int iz = (int)(pz * (float)GRID_RES);
        ix = min(max(ix, 0), GRID_RES-1);
        iy = min(max(iy, 0), GRID_RES-1);
        iz = min(max(iz, 0), GRID_RES-1);
        unsigned lin = (unsigned)(((ix << 7) | iy) << 7 | iz);

        const float* rec = data + 28u * lin;
        float4 A = *(const float4*)(rec + offA);
        float4 B = *(const float4*)(rec + offB);

        float pr = wr[0]*A.x + wr[1]*A.y + wr[2]*A.z + wr[3]*A.w
                 + wr[4]*B.x + wr[5]*B.y + wr[6]*B.z + wr[7]*B.w;
        float pg = wg[0]*A.x + wg[1]*A.y + wg[2]*A.z + wg[3]*A.w
                 + wg[4]*B.x + wg[5]*B.y + wg[6]*B.z + wg[7]*B.w;
        float pb = wb[0]*A.x + wb[1]*A.y + wb[2]*A.z + wb[3]*A.w
                 + wb[4]*B.x + wb[5]*B.y + wb[6]*B.z + wb[7]*B.w;

        float r = quad_sum(pr);
        float g = quad_sum(pg);
        float b = quad_sum(pb);
        float sigma = fmaxf(quad_bcast3(A.w), 0.0f);  // lane3's A.w == comp 27

        float att = __expf(-delta_t * sigma);
        float w = light * (1.0f - att);

        o_r = fmaf(w, sigmoidf_fast(r), o_r);
        o_g = fmaf(w, sigmoidf_fast(g), o_g);
        o_b = fmaf(w, sigmoidf_fast(b), o_b);
        light *= att;
    }

    if (l == 0) {
        out[3*ray+0] = o_r + light;   // BG = 1.0
        out[3*ray+1] = o_g + light;
        out[3*ray+2] = o_b + light;
    }
}

extern "C" void kernel_launch(void* const* d_in, const int* in_sizes, int n_in,
                              void* d_out, int out_size, void* d_ws, size_t ws_size,
                              hipStream_t stream) {
    const float* data     = (const float*)d_in[0];
    const float* origins  = (const float*)d_in[1];
    const float* dirs     = (const float*)d_in[2];
    const float* viewdirs = (const float*)d_in[3];
    float* out = (float*)d_out;

    dim3 block(256);
    dim3 grid((N_RAYS * 4) / 256);
    vr_kernel<<<grid, block, 0, stream>>>(data, origins, dirs, viewdirs, out);
}

// Round 5
// 121.991 us; speedup vs baseline: 2.0704x; 1.1318x over previous
//
#include <hip/hip_runtime.h>

#define GRID_RES 128
#define N_RAYS 65536
#define N_STEPS 128
#define STEP_SIZE 0.001f

__device__ __forceinline__ float sigmoidf_fast(float x) {
    return 1.0f / (1.0f + __expf(-x));
}

// DPP quad_perm helpers (cross-lane within aligned groups of 4 lanes)
__device__ __forceinline__ float quad_dpp_xor1(float x) {
    return __int_as_float(__builtin_amdgcn_update_dpp(0, __float_as_int(x), 0xB1, 0xF, 0xF, true)); // [1,0,3,2]
}
__device__ __forceinline__ float quad_dpp_xor2(float x) {
    return __int_as_float(__builtin_amdgcn_update_dpp(0, __float_as_int(x), 0x4E, 0xF, 0xF, true)); // [2,3,0,1]
}
__device__ __forceinline__ float quad_sum(float x) {
    x += quad_dpp_xor1(x);
    x += quad_dpp_xor2(x);
    return x;
}

__global__ __launch_bounds__(256) void vr_kernel(
    const float* __restrict__ data,
    const float* __restrict__ origins,
    const float* __restrict__ dirs,
    const float* __restrict__ viewdirs,
    float* __restrict__ out)
{
    int gid = blockIdx.x * blockDim.x + threadIdx.x;
    int ray = gid >> 2;        // 4 cooperative lanes per ray
    int l   = gid & 3;

    float ox = origins[3*ray+0], oy = origins[3*ray+1], oz = origins[3*ray+2];
    float dx = dirs[3*ray+0],    dy = dirs[3*ray+1],    dz = dirs[3*ray+2];
    float vx = viewdirs[3*ray+0], vy = viewdirs[3*ray+1], vz = viewdirs[3*ray+2];

    // normalize (numpy rounding: no fma contraction, sqrt+divide)
    {
        float s = __fadd_rn(__fadd_rn(__fmul_rn(dx,dx), __fmul_rn(dy,dy)), __fmul_rn(dz,dz));
        float n = sqrtf(s);
        dx = __fdiv_rn(dx, n); dy = __fdiv_rn(dy, n); dz = __fdiv_rn(dz, n);
    }
    {
        float s = __fadd_rn(__fadd_rn(__fmul_rn(vx,vx), __fmul_rn(vy,vy)), __fmul_rn(vz,vz));
        float n = sqrtf(s);
        vx = __fdiv_rn(vx, n); vy = __fdiv_rn(vy, n); vz = __fdiv_rn(vz, n);
    }

    float invx = __fdiv_rn(1.0f, __fadd_rn(dx, 1e-9f));
    float invy = __fdiv_rn(1.0f, __fadd_rn(dy, 1e-9f));
    float invz = __fdiv_rn(1.0f, __fadd_rn(dz, 1e-9f));

    float t1x = __fmul_rn(-ox, invx), t1y = __fmul_rn(-oy, invy), t1z = __fmul_rn(-oz, invz);
    float t2x = __fadd_rn(t1x, invx), t2y = __fadd_rn(t1y, invy), t2z = __fadd_rn(t1z, invz);
    float tmin = fmaxf(fmaxf(fminf(t1x,t2x), fminf(t1y,t2y)), fminf(t1z,t2z));
    tmin = fmaxf(tmin, 0.0f);
    float tmax = fminf(fminf(fmaxf(t1x,t2x), fmaxf(t1y,t2y)), fmaxf(t1z,t2z));
    tmax = fminf(tmax, 1e9f);
    float dt = __fmul_rn(fmaxf(__fsub_rn(tmax, tmin), 0.0f), (1.0f/(float)N_STEPS));
    float delta_t = __fadd_rn(dt, STEP_SIZE);

    // SH basis
    const float sh0 = 0.28209479177387814f;
    float sh1 = -0.4886025119029199f * vy;
    float sh2 =  0.4886025119029199f * vz;
    float sh3 = -0.4886025119029199f * vx;
    float sh4 =  1.0925484305920792f * vx * vy;
    float sh5 = -1.0925484305920792f * vy * vz;
    float sh6 =  0.31539156525252005f * (2.0f*vz*vz - vx*vx - vy*vy);
    float sh7 = -1.0925484305920792f * vx * vz;
    float sh8 =  0.5462742152960396f * (vx*vx - vy*vy);

    // Per-lane channel-routed weights for components c = 8l..8l+7 (zeros off-channel).
    float wr[8], wg[8], wb[8];
    #pragma unroll
    for (int m = 0; m < 8; ++m) {
        int c  = 8*l + m;
        int cb = c % 9;
        float s = sh0;
        s = (cb==1) ? sh1 : s;
        s = (cb==2) ? sh2 : s;
        s = (cb==3) ? sh3 : s;
        s = (cb==4) ? sh4 : s;
        s = (cb==5) ? sh5 : s;
        s = (cb==6) ? sh6 : s;
        s = (cb==7) ? sh7 : s;
        s = (cb==8) ? sh8 : s;
        wr[m] = (c < 9)            ? s : 0.0f;
        wg[m] = (c >= 9 && c < 18) ? s : 0.0f;
        wb[m] = (c >= 18 && c < 27)? s : 0.0f;
    }

    unsigned offA = 8u * (unsigned)l;
    unsigned offB = (l < 3) ? (8u * (unsigned)l + 4u) : 24u;

    // voxel linear index for step i — bit-identical to the validated chain
    auto linidx = [&](int i) -> unsigned {
        float t = __fadd_rn(tmin, __fmul_rn((float)i + 0.5f, dt));
        float px = __fadd_rn(ox, __fmul_rn(t, dx));
        float py = __fadd_rn(oy, __fmul_rn(t, dy));
        float pz = __fadd_rn(oz, __fmul_rn(t, dz));
        int ix = (int)(px * (float)GRID_RES);
        int iy = (int)(py * (float)GRID_RES);
        int iz = (int)(pz * (float)GRID_RES);
        ix = min(max(ix, 0), GRID_RES-1);
        iy = min(max(iy, 0), GRID_RES-1);
        iz = min(max(iz, 0), GRID_RES-1);
        return (unsigned)(((ix << 7) | iy) << 7 | iz);
    };

    float light = 1.0f;
    float o_r = 0.0f, o_g = 0.0f, o_b = 0.0f;

    // ---- 3-stage pipeline: sigma(i+2) || coeffs(i+1) || shade(i) ----
    // sigma: 4B load, same address on all 4 lanes (coalesces to one sector).
    // coeffs: address redirected to hot array base when sigma<=0 (no new line fills).
    unsigned lin1;
    float s0, s1;
    float4 A0, B0;
    {
        unsigned lin0 = linidx(0);
        lin1 = linidx(1);
        s0 = data[28u * lin0 + 27u];
        s1 = data[28u * lin1 + 27u];
        const float* rec0 = (s0 > 0.0f) ? (data + 28u * lin0) : data;
        A0 = *(const float4*)(rec0 + offA);
        B0 = *(const float4*)(rec0 + offB);
    }

    for (int i = 0; i < N_STEPS; ++i) {
        // stage 1: sigma two steps ahead (clamped index math is safe past 127)
        unsigned lin2 = linidx(i + 2);
        float s2 = data[28u * lin2 + 27u];

        // stage 2: coefficients one step ahead, σ-gated via address select
        const float* rec1 = (s1 > 0.0f) ? (data + 28u * lin1) : data;
        float4 A1 = *(const float4*)(rec1 + offA);
        float4 B1 = *(const float4*)(rec1 + offB);

        // stage 3: shade step i (branchless — w==0 exactly when s0<=0)
        float sigma = fmaxf(s0, 0.0f);
        float att = __expf(-delta_t * sigma);
        float w = light * (1.0f - att);

        float pr = wr[0]*A0.x + wr[1]*A0.y + wr[2]*A0.z + wr[3]*A0.w
                 + wr[4]*B0.x + wr[5]*B0.y + wr[6]*B0.z + wr[7]*B0.w;
        float pg = wg[0]*A0.x + wg[1]*A0.y + wg[2]*A0.z + wg[3]*A0.w
                 + wg[4]*B0.x + wg[5]*B0.y + wg[6]*B0.z + wg[7]*B0.w;
        float pb = wb[0]*A0.x + wb[1]*A0.y + wb[2]*A0.z + wb[3]*A0.w
                 + wb[4]*B0.x + wb[5]*B0.y + wb[6]*B0.z + wb[7]*B0.w;

        float r = quad_sum(pr);
        float g = quad_sum(pg);
        float b = quad_sum(pb);

        o_r = fmaf(w, sigmoidf_fast(r), o_r);
        o_g = fmaf(w, sigmoidf_fast(g), o_g);
        o_b = fmaf(w, sigmoidf_fast(b), o_b);
        light *= att;

        // shift pipeline (all static — no dynamic register indexing)
        s0 = s1; s1 = s2;
        lin1 = lin2;
        A0 = A1; B0 = B1;
    }

    if (l == 0) {
        out[3*ray+0] = o_r + light;   // BG = 1.0
        out[3*ray+1] = o_g + light;
        out[3*ray+2] = o_b + light;
    }
}

extern "C" void kernel_launch(void* const* d_in, const int* in_sizes, int n_in,
                              void* d_out, int out_size, void* d_ws, size_t ws_size,
                              hipStream_t stream) {
    const float* data     = (const float*)d_in[0];
    const float* origins  = (const float*)d_in[1];
    const float* dirs     = (const float*)d_in[2];
    const float* viewdirs = (const float*)d_in[3];
    float* out = (float*)d_out;

    dim3 block(256);
    dim3 grid((N_RAYS * 4) / 256);
    vr_kernel<<<grid, block, 0, stream>>>(data, origins, dirs, viewdirs, out);
}